// Round 1
// baseline (424.371 us; speedup 1.0000x reference)
//
#include <hip/hip_runtime.h>
#include <math.h>

#define H 1024
#define V 50257
#define L 512
#define RPB 32                       // vocab rows per block in k5
#define NPART ((V + RPB - 1) / RPB)  // 1571 logits blocks -> (max, sumexp) partials

__device__ inline float wave_reduce_sum(float v) {
    #pragma unroll
    for (int off = 32; off > 0; off >>= 1)
        v += __shfl_down(v, off, 64);
    return v;
}

__device__ inline float wave_reduce_max(float v) {
    #pragma unroll
    for (int off = 32; off > 0; off >>= 1)
        v = fmaxf(v, __shfl_down(v, off, 64));
    return v;
}

__device__ inline float dot4(float4 a, float4 b) {
    return a.x * b.x + a.y * b.y + a.z * b.z + a.w * b.w;
}

__device__ inline float sigmoidf_(float x) { return 1.f / (1.f + expf(-x)); }

// K1: fused (a) attention scores, (b) gh = W_hh @ h0 + b_hh (input-only dep),
// (c) zero attnap accumulator. Wave-per-row, 4 rows/block.
// blocks [0,128): scores rows; blocks [128,896): gh rows; block 896: zero.
__global__ void k1_scores_gh(const int* __restrict__ x,
                             const float* __restrict__ emb,
                             const float* __restrict__ hidden,
                             const float* __restrict__ attn_W,
                             const float* __restrict__ attn_b,
                             const float* __restrict__ W_hh,
                             const float* __restrict__ b_hh,
                             float* __restrict__ scores,
                             float* __restrict__ gh,
                             float* __restrict__ attnap) {
    const int b = blockIdx.x;
    const int t = threadIdx.x;
    const int lid = t & 63, wid = t >> 6;
    const float4* hv = (const float4*)hidden;          // 256 float4
    if (b < 128) {
        const int l = b * 4 + wid;
        const int xi = x[0];
        const float4* ev = (const float4*)(emb + (size_t)xi * H);
        const float4* wrow = (const float4*)(attn_W + (size_t)l * (2 * H)); // 512 f4
        float acc = 0.f;
        #pragma unroll
        for (int k = 0; k < 4; ++k) {
            int idx = k * 64 + lid;
            acc += dot4(ev[idx], wrow[idx]);
        }
        #pragma unroll
        for (int k = 0; k < 4; ++k) {
            int idx = k * 64 + lid;
            acc += dot4(hv[idx], wrow[256 + idx]);
        }
        acc = wave_reduce_sum(acc);
        if (lid == 0) scores[l] = acc + attn_b[l];
    } else if (b < 896) {
        const int r = (b - 128) * 4 + wid;
        const float4* wrow = (const float4*)(W_hh + (size_t)r * H);  // 256 f4
        float acc = 0.f;
        #pragma unroll
        for (int k = 0; k < 4; ++k) {
            int idx = k * 64 + lid;
            acc += dot4(hv[idx], wrow[idx]);
        }
        acc = wave_reduce_sum(acc);
        if (lid == 0) gh[r] = acc + b_hh[r];
    } else {
        ((float4*)attnap)[t] = make_float4(0.f, 0.f, 0.f, 0.f);
    }
}

// K2: redundant in-block softmax (2 KB, L2-hot) + attn_apply slice.
// grid (4 h-chunks, 16 l-chunks) x 256 threads. attnap += partial.
__global__ void k2_softmax_apply(const float* __restrict__ scores,
                                 const float* __restrict__ enc,
                                 float* __restrict__ attnap,
                                 float* __restrict__ out_attn) {
    const int t = threadIdx.x;              // 256
    __shared__ float smx[4], sms[4], sw[512];
    float v0 = scores[t], v1 = scores[t + 256];
    float m = wave_reduce_max(fmaxf(v0, v1));
    if ((t & 63) == 0) smx[t >> 6] = m;
    __syncthreads();
    float M = fmaxf(fmaxf(smx[0], smx[1]), fmaxf(smx[2], smx[3]));
    float e0 = expf(v0 - M), e1 = expf(v1 - M);
    float s = wave_reduce_sum(e0 + e1);
    if ((t & 63) == 0) sms[t >> 6] = s;
    __syncthreads();
    float S = sms[0] + sms[1] + sms[2] + sms[3];
    float w0 = e0 / S, w1 = e1 / S;
    sw[t] = w0;
    sw[t + 256] = w1;
    if (blockIdx.x == 0 && blockIdx.y == 0) {
        out_attn[t] = w0;
        out_attn[t + 256] = w1;
    }
    __syncthreads();
    const int h = blockIdx.x * 256 + t;
    const int l0 = blockIdx.y * 32;
    float acc = 0.f;
    #pragma unroll 8
    for (int i = 0; i < 32; ++i)
        acc += sw[l0 + i] * enc[(size_t)(l0 + i) * H + h];
    atomicAdd(&attnap[h], acc);
}

// K3: gru_in[r] = relu(comb_W[r,:2048] . [emb[x], attnap] + comb_b[r])
// wave-per-row, 4 rows/block, 256 blocks.
__global__ void k3_combine(const int* __restrict__ x,
                           const float* __restrict__ emb,
                           const float* __restrict__ attnap,
                           const float* __restrict__ comb_W,
                           const float* __restrict__ comb_b,
                           float* __restrict__ gru_in) {
    const int t = threadIdx.x;
    const int lid = t & 63, wid = t >> 6;
    const int r = blockIdx.x * 4 + wid;
    const int xi = x[0];
    const float4* ev = (const float4*)(emb + (size_t)xi * H);
    const float4* av = (const float4*)attnap;
    const float4* wrow = (const float4*)(comb_W + (size_t)r * (2 * H));
    float acc = 0.f;
    #pragma unroll
    for (int k = 0; k < 4; ++k) {
        int idx = k * 64 + lid;
        acc += dot4(ev[idx], wrow[idx]);
    }
    #pragma unroll
    for (int k = 0; k < 4; ++k) {
        int idx = k * 64 + lid;
        acc += dot4(av[idx], wrow[256 + idx]);
    }
    acc = wave_reduce_sum(acc);
    if (lid == 0) gru_in[r] = fmaxf(acc + comb_b[r], 0.f);
}

// K4: gx[r] = W_ih[r] . gru_in + b_ih[r]; wave-per-row, 768 blocks.
__global__ void k4_gx(const float* __restrict__ W_ih,
                      const float* __restrict__ b_ih,
                      const float* __restrict__ gru_in,
                      float* __restrict__ gx) {
    const int t = threadIdx.x;
    const int lid = t & 63, wid = t >> 6;
    const int r = blockIdx.x * 4 + wid;
    const float4* vv = (const float4*)gru_in;
    const float4* wrow = (const float4*)(W_ih + (size_t)r * H);
    float acc = 0.f;
    #pragma unroll
    for (int k = 0; k < 4; ++k) {
        int idx = k * 64 + lid;
        acc += dot4(vv[idx], wrow[idx]);
    }
    acc = wave_reduce_sum(acc);
    if (lid == 0) gx[r] = acc + b_ih[r];
}

// K5: fused GRU elementwise (redundant per block, L2-hot) + logits GEMV.
// 32 rows/block (4 waves x 8 rows), NPART blocks. Emits (max, sumexp) partials.
// All 8 row-accumulators issue their loads before any reduction runs (MLP depth).
__global__ void k5_cell_logits(const float* __restrict__ gx,
                               const float* __restrict__ gh,
                               const float* __restrict__ hidden,
                               const float* __restrict__ out_W,
                               const float* __restrict__ out_b,
                               float* __restrict__ logits,
                               float* __restrict__ partials) {
    const int t = threadIdx.x;              // 256
    __shared__ float sh[H];
    __shared__ float sl[RPB];
    // h_new[4t..4t+3]
    {
        float4 xr = ((const float4*)gx)[t];
        float4 xz = ((const float4*)(gx + H))[t];
        float4 xn = ((const float4*)(gx + 2 * H))[t];
        float4 hr = ((const float4*)gh)[t];
        float4 hz = ((const float4*)(gh + H))[t];
        float4 hn = ((const float4*)(gh + 2 * H))[t];
        float4 h0 = ((const float4*)hidden)[t];
        float4 o;
        {
            float r = sigmoidf_(xr.x + hr.x), z = sigmoidf_(xz.x + hz.x);
            float n = tanhf(xn.x + r * hn.x);
            o.x = (1.f - z) * n + z * h0.x;
        }
        {
            float r = sigmoidf_(xr.y + hr.y), z = sigmoidf_(xz.y + hz.y);
            float n = tanhf(xn.y + r * hn.y);
            o.y = (1.f - z) * n + z * h0.y;
        }
        {
            float r = sigmoidf_(xr.z + hr.z), z = sigmoidf_(xz.z + hz.z);
            float n = tanhf(xn.z + r * hn.z);
            o.z = (1.f - z) * n + z * h0.z;
        }
        {
            float r = sigmoidf_(xr.w + hr.w), z = sigmoidf_(xz.w + hz.w);
            float n = tanhf(xn.w + r * hn.w);
            o.w = (1.f - z) * n + z * h0.w;
        }
        ((float4*)sh)[t] = o;
    }
    __syncthreads();
    const int lid = t & 63, wid = t >> 6;
    const float4* hv = (const float4*)sh;
    float4 h0 = hv[lid], h1 = hv[64 + lid], h2 = hv[128 + lid], h3 = hv[192 + lid];
    const int vbase = blockIdx.x * RPB + wid * 8;
    float acc[8];
    #pragma unroll
    for (int rr = 0; rr < 8; ++rr) {
        const int v = vbase + rr;                // wave-uniform
        if (v < V) {
            const float4* wr = (const float4*)(out_W + (size_t)v * H);
            acc[rr] = dot4(wr[lid], h0) + dot4(wr[64 + lid], h1)
                    + dot4(wr[128 + lid], h2) + dot4(wr[192 + lid], h3);
        } else {
            acc[rr] = 0.f;
        }
    }
    #pragma unroll
    for (int rr = 0; rr < 8; ++rr) {
        const int v = vbase + rr;
        float a = wave_reduce_sum(acc[rr]);
        float val = -INFINITY;
        if (lid == 0) {
            if (v < V) { val = a + out_b[v]; logits[v] = val; }
            sl[wid * 8 + rr] = val;
        }
    }
    __syncthreads();
    if (t == 0) {
        float M = -INFINITY;
        #pragma unroll
        for (int i = 0; i < RPB; ++i) M = fmaxf(M, sl[i]);
        float S = 0.f;
        #pragma unroll
        for (int i = 0; i < RPB; ++i) S += expf(sl[i] - M);  // exp(-inf - M) = 0 for pad rows
        partials[2 * blockIdx.x] = M;
        partials[2 * blockIdx.x + 1] = S;
    }
}

// K6: each block redundantly reduces partials (12.5 KB, L2-hot) then
// subtracts logsumexp from its 512-logit chunk.
__global__ void k6_finalize(float* __restrict__ logits,
                            const float* __restrict__ partials) {
    const int t = threadIdx.x;              // 512
    __shared__ float sm[8];
    float m = -INFINITY;
    for (int i = t; i < NPART; i += 512) m = fmaxf(m, partials[2 * i]);
    m = wave_reduce_max(m);
    if ((t & 63) == 0) sm[t >> 6] = m;
    __syncthreads();
    float M = sm[0];
    #pragma unroll
    for (int i = 1; i < 8; ++i) M = fmaxf(M, sm[i]);
    __syncthreads();
    float s = 0.f;
    for (int i = t; i < NPART; i += 512) s += partials[2 * i + 1] * expf(partials[2 * i] - M);
    s = wave_reduce_sum(s);
    if ((t & 63) == 0) sm[t >> 6] = s;
    __syncthreads();
    float S = 0.f;
    #pragma unroll
    for (int i = 0; i < 8; ++i) S += sm[i];
    const float red = M + logf(S);
    const int v = blockIdx.x * 512 + t;
    if (v < V) logits[v] -= red;
}

extern "C" void kernel_launch(void* const* d_in, const int* in_sizes, int n_in,
                              void* d_out, int out_size, void* d_ws, size_t ws_size,
                              hipStream_t stream) {
    const int*   x       = (const int*)d_in[0];
    const float* enc     = (const float*)d_in[1];
    const float* hidden  = (const float*)d_in[2];
    const float* emb     = (const float*)d_in[3];
    const float* attn_W  = (const float*)d_in[4];
    const float* attn_b  = (const float*)d_in[5];
    const float* comb_W  = (const float*)d_in[6];
    const float* comb_b  = (const float*)d_in[7];
    const float* W_ih    = (const float*)d_in[8];
    const float* W_hh    = (const float*)d_in[9];
    const float* b_ih    = (const float*)d_in[10];
    const float* b_hh    = (const float*)d_in[11];
    const float* out_W   = (const float*)d_in[12];
    const float* out_b   = (const float*)d_in[13];
    float* out = (float*)d_out;
    float* ws  = (float*)d_ws;

    float* scores   = ws;            // 512
    float* attnap   = ws + 512;      // 1024
    float* gru_in   = ws + 1536;     // 1024
    float* gx       = ws + 2560;     // 3072
    float* gh       = ws + 5632;     // 3072
    float* partials = ws + 8704;     // 2*NPART

    k1_scores_gh<<<897, 256, 0, stream>>>(x, emb, hidden, attn_W, attn_b,
                                          W_hh, b_hh, scores, gh, attnap);
    k2_softmax_apply<<<dim3(4, 16), 256, 0, stream>>>(scores, enc, attnap, out + V);
    k3_combine<<<256, 256, 0, stream>>>(x, emb, attnap, comb_W, comb_b, gru_in);
    k4_gx<<<768, 256, 0, stream>>>(W_ih, b_ih, gru_in, gx);
    k5_cell_logits<<<NPART, 256, 0, stream>>>(gx, gh, hidden, out_W, out_b, out, partials);
    k6_finalize<<<(V + 511) / 512, 512, 0, stream>>>(out, partials);
}